// Round 7
// baseline (119.985 us; speedup 1.0000x reference)
//
#include <hip/hip_runtime.h>

typedef __attribute__((ext_vector_type(4))) _Float16 half4;
typedef __attribute__((ext_vector_type(4))) float floatx4;
typedef __attribute__((ext_vector_type(2))) unsigned uint2v;

#define NH 8
#define CHUNKS 4

struct Split2 { unsigned hi, lo; };

// s pre-scaled by 2*log2(e): tanh(a) = 1 - 2/(2^s + 1).
// hi = RTZ-f16 (exact via cvt_pkrtz), lo = (t - hi)*2^11 (f16-normal range).
// Saturation safe: E=inf -> rcp=0 -> t=1; E=0 -> t=-1 (lo=0 both ways).
__device__ __forceinline__ Split2 tanh_split2(float s0, float s1) {
    float E0 = __builtin_amdgcn_exp2f(s0);
    float E1 = __builtin_amdgcn_exp2f(s1);
    float r0 = __builtin_amdgcn_rcpf(E0 + 1.0f);
    float r1 = __builtin_amdgcn_rcpf(E1 + 1.0f);
    float t0 = fmaf(-2.0f, r0, 1.0f);
    float t1 = fmaf(-2.0f, r1, 1.0f);
    unsigned hp = __builtin_bit_cast(unsigned, __builtin_amdgcn_cvt_pkrtz(t0, t1));
    float h0 = (float)__builtin_bit_cast(_Float16, (unsigned short)(hp & 0xffffu));
    float h1 = (float)__builtin_bit_cast(_Float16, (unsigned short)(hp >> 16));
    float l0 = (t0 - h0) * 2048.0f;
    float l1 = (t1 - h1) * 2048.0f;
    Split2 r;
    r.hi = hp;
    r.lo = __builtin_bit_cast(unsigned, __builtin_amdgcn_cvt_pkrtz(l0, l1));
    return r;
}

__device__ __forceinline__ void split_w(float w, float& hi, float& lo) {
    _Float16 h = (_Float16)w;             // RNE
    hi = (float)h;
    lo = (w - hi) * 2048.0f;
}

__global__ __launch_bounds__(256, 8) void cppn_kernel(
    const float* __restrict__ x,
    const float* __restrict__ W0,
    const float* __restrict__ b0,
    const float* __restrict__ Wh,
    const float* __restrict__ bh,
    const float* __restrict__ Wo,
    const float* __restrict__ bo,
    float* __restrict__ out)
{
    // LDS-staged weights: frees ~48 persistent VGPRs vs register preload.
    __shared__ uint2v  s_whi[NH][64];   // 4 KB  hi f16x4 A-fragments
    __shared__ uint2v  s_wlo[NH][64];   // 4 KB  lo f16x4 A-fragments
    __shared__ floatx4 s_bias[NH][4];   // 512 B bias C-fragments [l][kg]
    __shared__ floatx4 s_w0f[4][4];     // 256 B input layer [r][g] = row g*4+r
    __shared__ floatx4 s_wo4[4];        // 64 B  output layer [kg]

    const int tid  = threadIdx.x;
    const int lane = tid & 63;
    const int col  = lane & 15;   // MFMA j (point within tile) / A row i
    const int kg   = lane >> 4;   // k-group 0..3
    const int wib  = tid >> 6;

    const float TSCL = 2.8853900817779268f;   // 2*log2(e): tanh pre-scale
    const float OSCL = -1.4426950408889634f;  // -log2(e): sigmoid pre-scale
    const float UNSC = 4.8828125e-4f;         // 2^-11

    // ---- stage weights into LDS (wave 0: hidden W; wave 1: bias/W0/Wo) ----
    if (tid < 64) {
        const int scol = tid & 15, skg = tid >> 4;
        #pragma unroll
        for (int l = 0; l < NH; ++l) {
            const float* wrow = Wh + l*256 + scol*16 + skg*4;
            float h0,h1,h2,h3, lo0,lo1,lo2,lo3;
            split_w(wrow[0]*TSCL, h0, lo0);
            split_w(wrow[1]*TSCL, h1, lo1);
            split_w(wrow[2]*TSCL, h2, lo2);
            split_w(wrow[3]*TSCL, h3, lo3);
            uint2v ha, la;
            ha.x = __builtin_bit_cast(unsigned, __builtin_amdgcn_cvt_pkrtz(h0, h1));
            ha.y = __builtin_bit_cast(unsigned, __builtin_amdgcn_cvt_pkrtz(h2, h3));
            la.x = __builtin_bit_cast(unsigned, __builtin_amdgcn_cvt_pkrtz(lo0, lo1));
            la.y = __builtin_bit_cast(unsigned, __builtin_amdgcn_cvt_pkrtz(lo2, lo3));
            s_whi[l][tid] = ha;
            s_wlo[l][tid] = la;
        }
    } else if (tid < 96) {
        const int t = tid - 64, l = t >> 2, g = t & 3;
        const float* bp = bh + l*16 + g*4;
        floatx4 c; c[0]=bp[0]*TSCL; c[1]=bp[1]*TSCL; c[2]=bp[2]*TSCL; c[3]=bp[3]*TSCL;
        s_bias[l][g] = c;
    } else if (tid < 112) {
        const int t = tid - 96, r = t & 3, g = t >> 2, row = g*4 + r;
        floatx4 v;
        v[0] = W0[row*3+0]*TSCL; v[1] = W0[row*3+1]*TSCL;
        v[2] = W0[row*3+2]*TSCL; v[3] = b0[row]*TSCL;
        s_w0f[r][g] = v;
    } else if (tid < 116) {
        const int g = tid - 112;
        floatx4 v;
        v[0]=Wo[g*4+0]*OSCL; v[1]=Wo[g*4+1]*OSCL; v[2]=Wo[g*4+2]*OSCL; v[3]=Wo[g*4+3]*OSCL;
        s_wo4[g] = v;
    }
    __syncthreads();

    const float bo2 = bo[0] * OSCL;
    const floatx4 zeroC = {0.0f, 0.0f, 0.0f, 0.0f};
    const long base0 = ((long)blockIdx.x * 4 + wib) * (64L * CHUNKS);

    #pragma unroll 1
    for (int c = 0; c < CHUNKS; ++c) {
        const long base = base0 + (long)c * 64;

        // ---- input layer -> split B-fragments (4 tiles of 16 points) ----
        floatx4 w0v0 = s_w0f[0][kg], w0v1 = s_w0f[1][kg];
        floatx4 w0v2 = s_w0f[2][kg], w0v3 = s_w0f[3][kg];
        half4 hBhi[4], hBlo[4];
        #pragma unroll
        for (int t = 0; t < 4; ++t) {
            const long p = base + t*16 + col;
            const float x0 = x[p*3+0], x1 = x[p*3+1], x2 = x[p*3+2];
            float a0 = fmaf(w0v0[0],x0, fmaf(w0v0[1],x1, fmaf(w0v0[2],x2, w0v0[3])));
            float a1 = fmaf(w0v1[0],x0, fmaf(w0v1[1],x1, fmaf(w0v1[2],x2, w0v1[3])));
            float a2 = fmaf(w0v2[0],x0, fmaf(w0v2[1],x1, fmaf(w0v2[2],x2, w0v2[3])));
            float a3 = fmaf(w0v3[0],x0, fmaf(w0v3[1],x1, fmaf(w0v3[2],x2, w0v3[3])));
            Split2 p01 = tanh_split2(a0, a1);
            Split2 p23 = tanh_split2(a2, a3);
            uint2v hb, lb;
            hb.x = p01.hi; hb.y = p23.hi;
            lb.x = p01.lo; lb.y = p23.lo;
            hBhi[t] = __builtin_bit_cast(half4, hb);
            hBlo[t] = __builtin_bit_cast(half4, lb);
        }

        // ---- hidden layers 0..6: split-precision MFMA, tile pairs ----
        #pragma unroll
        for (int l = 0; l < NH-1; ++l) {
            const uint2v haw = s_whi[l][lane];
            const uint2v law = s_wlo[l][lane];
            const half4 whi = __builtin_bit_cast(half4, haw);
            const half4 wlo = __builtin_bit_cast(half4, law);
            const floatx4 bc = s_bias[l][kg];
            #pragma unroll
            for (int tp = 0; tp < 2; ++tp) {
                const int u0 = tp*2, u1 = tp*2+1;
                floatx4 d0 = __builtin_amdgcn_mfma_f32_16x16x16f16(whi, hBhi[u0], bc, 0,0,0);
                floatx4 d1 = __builtin_amdgcn_mfma_f32_16x16x16f16(whi, hBhi[u1], bc, 0,0,0);
                floatx4 e0 = __builtin_amdgcn_mfma_f32_16x16x16f16(whi, hBlo[u0], zeroC, 0,0,0);
                floatx4 e1 = __builtin_amdgcn_mfma_f32_16x16x16f16(whi, hBlo[u1], zeroC, 0,0,0);
                e0 = __builtin_amdgcn_mfma_f32_16x16x16f16(wlo, hBhi[u0], e0, 0,0,0);
                e1 = __builtin_amdgcn_mfma_f32_16x16x16f16(wlo, hBhi[u1], e1, 0,0,0);

                float s00 = fmaf(e0[0], UNSC, d0[0]);
                float s01 = fmaf(e0[1], UNSC, d0[1]);
                float s02 = fmaf(e0[2], UNSC, d0[2]);
                float s03 = fmaf(e0[3], UNSC, d0[3]);
                float s10 = fmaf(e1[0], UNSC, d1[0]);
                float s11 = fmaf(e1[1], UNSC, d1[1]);
                float s12 = fmaf(e1[2], UNSC, d1[2]);
                float s13 = fmaf(e1[3], UNSC, d1[3]);
                Split2 a01 = tanh_split2(s00, s01);
                Split2 a23 = tanh_split2(s02, s03);
                Split2 b01 = tanh_split2(s10, s11);
                Split2 b23 = tanh_split2(s12, s13);
                uint2v hb0, lb0, hb1, lb1;
                hb0.x = a01.hi; hb0.y = a23.hi;
                lb0.x = a01.lo; lb0.y = a23.lo;
                hb1.x = b01.hi; hb1.y = b23.hi;
                lb1.x = b01.lo; lb1.y = b23.lo;
                hBhi[u0] = __builtin_bit_cast(half4, hb0);
                hBlo[u0] = __builtin_bit_cast(half4, lb0);
                hBhi[u1] = __builtin_bit_cast(half4, hb1);
                hBlo[u1] = __builtin_bit_cast(half4, lb1);
            }
        }

        // ---- last hidden layer + output dot + sigmoid ----
        {
            const uint2v haw = s_whi[NH-1][lane];
            const uint2v law = s_wlo[NH-1][lane];
            const half4 whi = __builtin_bit_cast(half4, haw);
            const half4 wlo = __builtin_bit_cast(half4, law);
            const floatx4 bc = s_bias[NH-1][kg];
            const floatx4 wov = s_wo4[kg];
            float tot[4];
            #pragma unroll
            for (int t = 0; t < 4; ++t) {
                floatx4 d = __builtin_amdgcn_mfma_f32_16x16x16f16(whi, hBhi[t], bc, 0,0,0);
                floatx4 e = __builtin_amdgcn_mfma_f32_16x16x16f16(whi, hBlo[t], zeroC, 0,0,0);
                e = __builtin_amdgcn_mfma_f32_16x16x16f16(wlo, hBhi[t], e, 0,0,0);
                float acc = 0.0f;
                #pragma unroll
                for (int r = 0; r < 4; ++r) {
                    float sv = fmaf(e[r], UNSC, d[r]);
                    float E  = __builtin_amdgcn_exp2f(sv);
                    float rc = __builtin_amdgcn_rcpf(E + 1.0f);
                    float tt = fmaf(-2.0f, rc, 1.0f);
                    acc = fmaf(wov[r], tt, acc);
                }
                acc += __shfl_xor(acc, 16);
                acc += __shfl_xor(acc, 32);
                tot[t] = acc;
            }
            float s = (kg == 0) ? tot[0] : (kg == 1) ? tot[1] : (kg == 2) ? tot[2] : tot[3];
            s += bo2;
            float E = __builtin_amdgcn_exp2f(s);
            out[base + lane] = __builtin_amdgcn_rcpf(1.0f + E);
        }
    }
}

extern "C" void kernel_launch(void* const* d_in, const int* in_sizes, int n_in,
                              void* d_out, int out_size, void* d_ws, size_t ws_size,
                              hipStream_t stream) {
    const float* x  = (const float*)d_in[0];
    const float* W0 = (const float*)d_in[1];
    const float* b0 = (const float*)d_in[2];
    const float* Wh = (const float*)d_in[3];
    const float* bh = (const float*)d_in[4];
    const float* Wo = (const float*)d_in[5];
    const float* bo = (const float*)d_in[6];
    float* out = (float*)d_out;

    int n = out_size;                           // 2097152 = 2048 * 1024, exact
    int block = 256;                            // 4 waves
    long ptsPerBlock = 4L * 64 * CHUNKS;        // 1024
    int grid = (int)((n + ptsPerBlock - 1) / ptsPerBlock);   // 2048 = 8/CU
    cppn_kernel<<<grid, block, 0, stream>>>(x, W0, b0, Wh, bh, Wo, bo, out);
}

// Round 8
// 107.291 us; speedup vs baseline: 1.1183x; 1.1183x over previous
//
#include <hip/hip_runtime.h>

typedef __attribute__((ext_vector_type(4))) _Float16 half4;
typedef __attribute__((ext_vector_type(4))) float floatx4;
typedef __attribute__((ext_vector_type(2))) unsigned uint2v;

#define NH 8
#define CHUNKS 8

struct Split2 { unsigned hi, lo; };

// Split r0,r1 (each in [0,1]) into exact f16 hi (RTZ) + residual lo*2^11.
__device__ __forceinline__ Split2 split2(float t0, float t1) {
    unsigned hp = __builtin_bit_cast(unsigned, __builtin_amdgcn_cvt_pkrtz(t0, t1));
    float h0 = (float)__builtin_bit_cast(_Float16, (unsigned short)(hp & 0xffffu));
    float h1 = (float)__builtin_bit_cast(_Float16, (unsigned short)(hp >> 16));
    float l0 = (t0 - h0) * 2048.0f;
    float l1 = (t1 - h1) * 2048.0f;
    Split2 r;
    r.hi = hp;
    r.lo = __builtin_bit_cast(unsigned, __builtin_amdgcn_cvt_pkrtz(l0, l1));
    return r;
}

// r_i = 1/(2^min(s_i,25) + 1), one v_rcp (+1 Newton) for 4 activations.
// s<=25 => p<=2^25+1, P=(p0p1p2p3)<=~2^100: no overflow. p>=1: no underflow.
// tanh(a) = 1 - 2*r; the affine is folded into the consumer's weights.
__device__ __forceinline__ floatx4 quad_r(float s0, float s1, float s2, float s3) {
    s0 = fminf(s0, 25.0f); s1 = fminf(s1, 25.0f);
    s2 = fminf(s2, 25.0f); s3 = fminf(s3, 25.0f);
    float p0 = __builtin_amdgcn_exp2f(s0) + 1.0f;
    float p1 = __builtin_amdgcn_exp2f(s1) + 1.0f;
    float p2 = __builtin_amdgcn_exp2f(s2) + 1.0f;
    float p3 = __builtin_amdgcn_exp2f(s3) + 1.0f;
    float A = p0 * p1, B = p2 * p3;
    float P = A * B;
    float rp = __builtin_amdgcn_rcpf(P);
    rp = rp * fmaf(-P, rp, 2.0f);          // Newton: ~1 ulp on 1/P
    float rA = rp * B, rB = rp * A;
    floatx4 r;
    r[0] = rA * p1; r[1] = rA * p0; r[2] = rB * p3; r[3] = rB * p2;
    return r;
}

__device__ __forceinline__ void split_w(float w, float& hi, float& lo) {
    _Float16 h = (_Float16)w;              // RNE
    hi = (float)h;
    lo = (w - hi) * 2048.0f;
}

__global__ __launch_bounds__(256, 4) void cppn_kernel(
    const float* __restrict__ x,
    const float* __restrict__ W0,
    const float* __restrict__ b0,
    const float* __restrict__ Wh,
    const float* __restrict__ bh,
    const float* __restrict__ Wo,
    const float* __restrict__ bo,
    float* __restrict__ out)
{
    const int tid  = threadIdx.x;
    const int lane = tid & 63;
    const int col  = lane & 15;   // MFMA j (point) / A-fragment row i
    const int kg   = lane >> 4;   // k-group 0..3
    const int wib  = tid >> 6;

    const float TSCL = 2.8853900817779268f;    // 2*log2(e)
    const float NSCL = -2.0f * TSCL;           // feed-r hidden weight scale
    const float OSCL = -1.4426950408889634f;   // -log2(e)
    const float UNSC = 4.8828125e-4f;          // 2^-11

    // ---- preload hidden weights W' = NSCL*W (hi/lo split) + b' = TSCL*(b + rowsum W)
    // A[i=fo][k=fi]: lane holds i=col, k=kg*4+r  -> Wh[l][col][kg*4+r]
    // C/D[i][j=pt]:  lane holds i=kg*4+r, j=col
    half4   wAhi[NH], wAlo[NH];
    floatx4 bC[NH];
    #pragma unroll
    for (int l = 0; l < NH; ++l) {
        const float* wrow = Wh + l*256 + col*16 + kg*4;
        float w0 = wrow[0], w1 = wrow[1], w2 = wrow[2], w3 = wrow[3];
        // row-sum of row `col` across all 16 k (for the consumer-side bias fold)
        float rs = (w0 + w1) + (w2 + w3);
        rs += __shfl_xor(rs, 16);
        rs += __shfl_xor(rs, 32);
        float h0,h1,h2,h3, lo0,lo1,lo2,lo3;
        split_w(w0*NSCL, h0, lo0);
        split_w(w1*NSCL, h1, lo1);
        split_w(w2*NSCL, h2, lo2);
        split_w(w3*NSCL, h3, lo3);
        uint2v ha, la;
        ha.x = __builtin_bit_cast(unsigned, __builtin_amdgcn_cvt_pkrtz(h0, h1));
        ha.y = __builtin_bit_cast(unsigned, __builtin_amdgcn_cvt_pkrtz(h2, h3));
        la.x = __builtin_bit_cast(unsigned, __builtin_amdgcn_cvt_pkrtz(lo0, lo1));
        la.y = __builtin_bit_cast(unsigned, __builtin_amdgcn_cvt_pkrtz(lo2, lo3));
        wAhi[l] = __builtin_bit_cast(half4, ha);
        wAlo[l] = __builtin_bit_cast(half4, la);
        floatx4 c;
        #pragma unroll
        for (int r = 0; r < 4; ++r) {
            float rs_r = __shfl(rs, kg*4 + r);           // rowsum of row kg*4+r
            c[r] = TSCL * (bh[l*16 + kg*4 + r] + rs_r);
        }
        bC[l] = c;
    }

    // input layer (consumes x directly: plain TSCL scale, no feed-r transform)
    float w0r[4][3]; float b0r[4];
    #pragma unroll
    for (int r = 0; r < 4; ++r) {
        const float* wp = W0 + (kg*4 + r)*3;
        w0r[r][0] = wp[0]*TSCL; w0r[r][1] = wp[1]*TSCL; w0r[r][2] = wp[2]*TSCL;
        b0r[r] = b0[kg*4 + r]*TSCL;
    }

    // output layer: consumes r8 -> wo' = -2*OSCL*wo, bo' = OSCL*(bo + sum wo)
    float woP[4];
    float wsum;
    {
        const float* wp = Wo + kg*4;
        float a = wp[0], b = wp[1], c2 = wp[2], d = wp[3];
        wsum = (a + b) + (c2 + d);
        wsum += __shfl_xor(wsum, 16);
        wsum += __shfl_xor(wsum, 32);
        woP[0] = a*(-2.0f*OSCL); woP[1] = b*(-2.0f*OSCL);
        woP[2] = c2*(-2.0f*OSCL); woP[3] = d*(-2.0f*OSCL);
    }
    const float boP = OSCL * (bo[0] + wsum);

    const floatx4 zeroC = {0.0f, 0.0f, 0.0f, 0.0f};
    const long base0 = ((long)blockIdx.x * 4 + wib) * (64L * CHUNKS);

    #pragma unroll 1
    for (int c = 0; c < CHUNKS; ++c) {
        const long base = base0 + (long)c * 64;

        // ---- input layer -> split r-fragments (4 tiles of 16 points) ----
        half4 hBhi[4], hBlo[4];
        #pragma unroll
        for (int t = 0; t < 4; ++t) {
            const long p = base + t*16 + col;
            const float x0 = x[p*3+0], x1 = x[p*3+1], x2 = x[p*3+2];
            float a0 = fmaf(w0r[0][0],x0, fmaf(w0r[0][1],x1, fmaf(w0r[0][2],x2, b0r[0])));
            float a1 = fmaf(w0r[1][0],x0, fmaf(w0r[1][1],x1, fmaf(w0r[1][2],x2, b0r[1])));
            float a2 = fmaf(w0r[2][0],x0, fmaf(w0r[2][1],x1, fmaf(w0r[2][2],x2, b0r[2])));
            float a3 = fmaf(w0r[3][0],x0, fmaf(w0r[3][1],x1, fmaf(w0r[3][2],x2, b0r[3])));
            floatx4 rq = quad_r(a0, a1, a2, a3);
            Split2 p01 = split2(rq[0], rq[1]);
            Split2 p23 = split2(rq[2], rq[3]);
            uint2v hb, lb;
            hb.x = p01.hi; hb.y = p23.hi;
            lb.x = p01.lo; lb.y = p23.lo;
            hBhi[t] = __builtin_bit_cast(half4, hb);
            hBlo[t] = __builtin_bit_cast(half4, lb);
        }

        // ---- hidden layers 0..6: split MFMA -> quad-r -> split ----
        #pragma unroll
        for (int l = 0; l < NH-1; ++l) {
            const half4 whi = wAhi[l];
            const half4 wlo = wAlo[l];
            const floatx4 bc = bC[l];
            #pragma unroll
            for (int tp = 0; tp < 2; ++tp) {
                const int u0 = tp*2, u1 = tp*2+1;
                floatx4 d0 = __builtin_amdgcn_mfma_f32_16x16x16f16(whi, hBhi[u0], bc, 0,0,0);
                floatx4 d1 = __builtin_amdgcn_mfma_f32_16x16x16f16(whi, hBhi[u1], bc, 0,0,0);
                floatx4 e0 = __builtin_amdgcn_mfma_f32_16x16x16f16(whi, hBlo[u0], zeroC, 0,0,0);
                floatx4 e1 = __builtin_amdgcn_mfma_f32_16x16x16f16(whi, hBlo[u1], zeroC, 0,0,0);
                e0 = __builtin_amdgcn_mfma_f32_16x16x16f16(wlo, hBhi[u0], e0, 0,0,0);
                e1 = __builtin_amdgcn_mfma_f32_16x16x16f16(wlo, hBhi[u1], e1, 0,0,0);

                floatx4 q0 = quad_r(fmaf(e0[0], UNSC, d0[0]),
                                    fmaf(e0[1], UNSC, d0[1]),
                                    fmaf(e0[2], UNSC, d0[2]),
                                    fmaf(e0[3], UNSC, d0[3]));
                floatx4 q1 = quad_r(fmaf(e1[0], UNSC, d1[0]),
                                    fmaf(e1[1], UNSC, d1[1]),
                                    fmaf(e1[2], UNSC, d1[2]),
                                    fmaf(e1[3], UNSC, d1[3]));
                Split2 a01 = split2(q0[0], q0[1]);
                Split2 a23 = split2(q0[2], q0[3]);
                Split2 b01 = split2(q1[0], q1[1]);
                Split2 b23 = split2(q1[2], q1[3]);
                uint2v hb0, lb0, hb1, lb1;
                hb0.x = a01.hi; hb0.y = a23.hi;
                lb0.x = a01.lo; lb0.y = a23.lo;
                hb1.x = b01.hi; hb1.y = b23.hi;
                lb1.x = b01.lo; lb1.y = b23.lo;
                hBhi[u0] = __builtin_bit_cast(half4, hb0);
                hBlo[u0] = __builtin_bit_cast(half4, lb0);
                hBhi[u1] = __builtin_bit_cast(half4, hb1);
                hBlo[u1] = __builtin_bit_cast(half4, lb1);
            }
        }

        // ---- last hidden layer -> r8 -> output dot (feed-r) + sigmoid ----
        float tot[4];
        #pragma unroll
        for (int t = 0; t < 4; ++t) {
            floatx4 d = __builtin_amdgcn_mfma_f32_16x16x16f16(wAhi[NH-1], hBhi[t], bC[NH-1], 0,0,0);
            floatx4 e = __builtin_amdgcn_mfma_f32_16x16x16f16(wAhi[NH-1], hBlo[t], zeroC, 0,0,0);
            e = __builtin_amdgcn_mfma_f32_16x16x16f16(wAlo[NH-1], hBhi[t], e, 0,0,0);
            floatx4 r8 = quad_r(fmaf(e[0], UNSC, d[0]),
                                fmaf(e[1], UNSC, d[1]),
                                fmaf(e[2], UNSC, d[2]),
                                fmaf(e[3], UNSC, d[3]));
            float acc = fmaf(woP[0], r8[0],
                        fmaf(woP[1], r8[1],
                        fmaf(woP[2], r8[2], woP[3] * r8[3])));
            acc += __shfl_xor(acc, 16);
            acc += __shfl_xor(acc, 32);
            tot[t] = acc;
        }

        float s = (kg == 0) ? tot[0] : (kg == 1) ? tot[1] : (kg == 2) ? tot[2] : tot[3];
        s += boP;
        float E = __builtin_amdgcn_exp2f(s);
        out[base + lane] = __builtin_amdgcn_rcpf(1.0f + E);
    }
}

extern "C" void kernel_launch(void* const* d_in, const int* in_sizes, int n_in,
                              void* d_out, int out_size, void* d_ws, size_t ws_size,
                              hipStream_t stream) {
    const float* x  = (const float*)d_in[0];
    const float* W0 = (const float*)d_in[1];
    const float* b0 = (const float*)d_in[2];
    const float* Wh = (const float*)d_in[3];
    const float* bh = (const float*)d_in[4];
    const float* Wo = (const float*)d_in[5];
    const float* bo = (const float*)d_in[6];
    float* out = (float*)d_out;

    int n = out_size;                           // 2097152 = 1024 * 2048, exact
    int block = 256;                            // 4 waves
    long ptsPerBlock = 4L * 64 * CHUNKS;        // 2048
    int grid = (int)((n + ptsPerBlock - 1) / ptsPerBlock);   // 1024 = 4/CU
    cppn_kernel<<<grid, block, 0, stream>>>(x, W0, b0, Wh, bh, Wo, bo, out);
}